// Round 2
// baseline (189.946 us; speedup 1.0000x reference)
//
#include <hip/hip_runtime.h>
#include <hip/hip_bf16.h>

#define TGT 256
#define BSZ 8
#define E   256
#define SRC 4096

typedef __attribute__((ext_vector_type(8))) short           bf16x8;
typedef __attribute__((ext_vector_type(4))) float           f32x4;
typedef __attribute__((ext_vector_type(4))) float           f4;
typedef __attribute__((ext_vector_type(8))) unsigned short  u16x8;

__device__ inline unsigned short f2b(float x) {
    union { __hip_bfloat16 h; unsigned short u; } cv;
    cv.h = __float2bfloat16(x);
    return cv.u;
}

// load 8 contiguous floats, convert to bf16x8 fragment
__device__ inline bf16x8 cvt8v(const float* __restrict__ p) {
    f4 lo = *(const f4*)p;
    f4 hi = *(const f4*)(p + 4);
    bf16x8 r;
    #pragma unroll
    for (int j = 0; j < 4; ++j) {
        r[j]     = (short)f2b(lo[j]);
        r[4 + j] = (short)f2b(hi[j]);
    }
    return r;
}

// ---------------------------------------------------------------------------
// Kernel 1: value(SRC,BSZ,E) fp32 -> vt[b][e][s] bf16   (64x64 tile / block)
// ---------------------------------------------------------------------------
__global__ __launch_bounds__(256) void transpose_v(
    const float* __restrict__ value, unsigned short* __restrict__ vt)
{
    __shared__ unsigned short tile[64 * 72];
    const int b  = blockIdx.z;
    const int e0 = blockIdx.y * 64;
    const int s0 = blockIdx.x * 64;
    const int tid = threadIdx.x;

    #pragma unroll
    for (int i = 0; i < 4; ++i) {
        int lin = i * 256 + tid;      // 0..1023
        int r   = lin >> 4;           // s-local 0..63
        int c4  = lin & 15;           // e float4 index
        f4 v = *(const f4*)(value + (size_t)(s0 + r) * (BSZ * E)
                                  + (size_t)b * E + e0 + c4 * 4);
        #pragma unroll
        for (int j = 0; j < 4; ++j)
            tile[(c4 * 4 + j) * 72 + r] = f2b(v[j]);   // store transposed
    }
    __syncthreads();
    #pragma unroll
    for (int i = 0; i < 2; ++i) {
        int lin = i * 256 + tid;      // 0..511
        int er  = lin >> 3;           // e-local 0..63
        int c8  = lin & 7;            // s vec index
        u16x8 v = *(const u16x8*)(tile + er * 72 + c8 * 8);
        *(u16x8*)(vt + (size_t)b * E * SRC + (size_t)(e0 + er) * SRC + s0 + c8 * 8) = v;
    }
}

// ---------------------------------------------------------------------------
// Kernel 2: attn_weights = proposal_mask (fp32 verbatim copy)
// ---------------------------------------------------------------------------
__global__ __launch_bounds__(256) void copy_mask(
    const f4* __restrict__ src, f4* __restrict__ dst, int nvec)
{
    int i      = blockIdx.x * blockDim.x + threadIdx.x;
    int stride = gridDim.x * blockDim.x;
    for (; i < nvec; i += stride) dst[i] = src[i];
}

// ---------------------------------------------------------------------------
// Kernel 3: per-b GEMM  C_b = M_b(256x4096) @ V_b(4096x256)
// mask fp32 (inline cvt), vt bf16. 512 blocks x 512 thr; 32x32 tile;
// 8 waves split K=4096 into 512-chunks; LDS fp32 reduction; fp32 cred out.
// ---------------------------------------------------------------------------
__global__ __launch_bounds__(512) void gemm1(
    const float* __restrict__ mask,
    const unsigned short* __restrict__ vt,
    float* __restrict__ c_red)
{
    __shared__ float red[8 * 32 * 32];   // 32 KB
    const int bx   = blockIdx.x;
    const int b    = bx & 7;             // XCD-locality swizzle
    const int tile = bx >> 3;            // 0..63
    const int t0   = (tile >> 3) * 32;
    const int e0   = (tile & 7) * 32;
    const int tid  = threadIdx.x;
    const int w    = tid >> 6;           // wave 0..7
    const int lane = tid & 63;
    const int quad = lane >> 4;
    const int l15  = lane & 15;

    const float* mrow0 = mask + (size_t)b * TGT * SRC + (size_t)(t0 + l15) * SRC;
    const float* mrow1 = mrow0 + 16 * SRC;
    const unsigned short* vrow0 = vt + (size_t)b * E * SRC + (size_t)(e0 + l15) * SRC;
    const unsigned short* vrow1 = vrow0 + 16 * SRC;
    const int kbase = w * 512 + quad * 8;

    f32x4 acc00 = {}, acc01 = {}, acc10 = {}, acc11 = {};
    #pragma unroll 4
    for (int ks = 0; ks < 16; ++ks) {
        int k = kbase + ks * 32;
        bf16x8 a0 = cvt8v(mrow0 + k);
        bf16x8 a1 = cvt8v(mrow1 + k);
        bf16x8 b0 = *(const bf16x8*)(vrow0 + k);
        bf16x8 b1 = *(const bf16x8*)(vrow1 + k);
        acc00 = __builtin_amdgcn_mfma_f32_16x16x32_bf16(a0, b0, acc00, 0, 0, 0);
        acc01 = __builtin_amdgcn_mfma_f32_16x16x32_bf16(a0, b1, acc01, 0, 0, 0);
        acc10 = __builtin_amdgcn_mfma_f32_16x16x32_bf16(a1, b0, acc10, 0, 0, 0);
        acc11 = __builtin_amdgcn_mfma_f32_16x16x32_bf16(a1, b1, acc11, 0, 0, 0);
    }

    // write 32x32 fp32 partial into this wave's LDS slab
    // D layout: col = lane&15, row = quad*4 + reg   [verified m89/m91]
    float* slab = red + w * 1024;
    #pragma unroll
    for (int r = 0; r < 4; ++r) {
        slab[( 0 + quad * 4 + r) * 32 + ( 0 + l15)] = acc00[r];
        slab[( 0 + quad * 4 + r) * 32 + (16 + l15)] = acc01[r];
        slab[(16 + quad * 4 + r) * 32 + ( 0 + l15)] = acc10[r];
        slab[(16 + quad * 4 + r) * 32 + (16 + l15)] = acc11[r];
    }
    __syncthreads();

    #pragma unroll
    for (int i = 0; i < 2; ++i) {
        int idx = i * 512 + tid;           // 0..1023
        float s = 0.f;
        #pragma unroll
        for (int ww = 0; ww < 8; ++ww) s += red[ww * 1024 + idx];
        int row = idx >> 5, col = idx & 31;
        c_red[(size_t)b * TGT * E + (size_t)(t0 + row) * E + (e0 + col)] = s;
    }
}

// ---------------------------------------------------------------------------
// Kernel 4: out[t,b,:] = C_b[t,:] @ W^T + bias   (per-b 256x256x256, fp32 io)
// wave per 16x16 tile; W rows are k-contiguous so direct frag loads.
// ---------------------------------------------------------------------------
__global__ __launch_bounds__(256) void gemm2(
    const float* __restrict__ c_red,
    const float* __restrict__ wgt,
    const float* __restrict__ bias,
    float* __restrict__ out0)
{
    const int tid  = threadIdx.x;
    const int wv   = tid >> 6;
    const int lane = tid & 63;
    const int tau  = blockIdx.x * 4 + wv;   // 0..2047
    const int b    = tau >> 8;
    const int rem  = tau & 255;
    const int t0   = (rem >> 4) * 16;
    const int e0   = (rem & 15) * 16;
    const int quad = lane >> 4;
    const int l15  = lane & 15;

    const float* arow = c_red + (size_t)b * TGT * E + (size_t)(t0 + l15) * E + quad * 8;
    const float* brow = wgt   + (size_t)(e0 + l15) * E + quad * 8;

    f32x4 acc = {};
    #pragma unroll
    for (int ks = 0; ks < 8; ++ks) {
        bf16x8 a  = cvt8v(arow + ks * 32);
        bf16x8 bb = cvt8v(brow + ks * 32);
        acc = __builtin_amdgcn_mfma_f32_16x16x32_bf16(a, bb, acc, 0, 0, 0);
    }

    const float bval = bias[e0 + l15];
    #pragma unroll
    for (int r = 0; r < 4; ++r) {
        int t = t0 + quad * 4 + r;
        int e = e0 + l15;
        out0[(size_t)t * (BSZ * E) + (size_t)b * E + e] = acc[r] + bval;
    }
}

// ---------------------------------------------------------------------------
extern "C" void kernel_launch(void* const* d_in, const int* in_sizes, int n_in,
                              void* d_out, int out_size, void* d_ws, size_t ws_size,
                              hipStream_t stream)
{
    // inputs: 0=query(unused) 1=key(unused) 2=value 3=proposal_mask 4=W 5=bias
    const float* value = (const float*)d_in[2];
    const float* mask  = (const float*)d_in[3];
    const float* wgt   = (const float*)d_in[4];
    const float* bias  = (const float*)d_in[5];

    float* out0 = (float*)d_out;                              // (256,8,256)
    float* out1 = (float*)d_out + (size_t)TGT * BSZ * E;      // (8,256,4096)

    unsigned short* vt   = (unsigned short*)d_ws;             // [b][e][s] bf16, 16.8 MB
    float*          cred = (float*)(vt + (size_t)BSZ * E * SRC); // [b][t][e] fp32, 2 MB

    transpose_v<<<dim3(SRC / 64, E / 64, BSZ), 256, 0, stream>>>(value, vt);
    copy_mask<<<2048, 256, 0, stream>>>((const f4*)mask, (f4*)out1,
                                        BSZ * TGT * SRC / 4);
    gemm1<<<512, 512, 0, stream>>>(mask, vt, cred);
    gemm2<<<512, 256, 0, stream>>>(cred, wgt, bias, out0);
}

// Round 3
// 177.239 us; speedup vs baseline: 1.0717x; 1.0717x over previous
//
#include <hip/hip_runtime.h>
#include <hip/hip_bf16.h>

#define TGT 256
#define BSZ 8
#define E   256
#define SRC 4096

typedef __attribute__((ext_vector_type(8))) short           bf16x8;
typedef __attribute__((ext_vector_type(4))) float           f32x4;
typedef __attribute__((ext_vector_type(4))) float           f4;
typedef __attribute__((ext_vector_type(8))) unsigned short  u16x8;
typedef __attribute__((ext_vector_type(4))) unsigned short  u16x4;

__device__ inline unsigned short f2b(float x) {
    union { __hip_bfloat16 h; unsigned short u; } cv;
    cv.h = __float2bfloat16(x);
    return cv.u;
}

// load 8 contiguous floats, convert to bf16x8 fragment
__device__ inline bf16x8 cvt8v(const float* __restrict__ p) {
    f4 lo = *(const f4*)p;
    f4 hi = *(const f4*)(p + 4);
    bf16x8 r;
    #pragma unroll
    for (int j = 0; j < 4; ++j) {
        r[j]     = (short)f2b(lo[j]);
        r[4 + j] = (short)f2b(hi[j]);
    }
    return r;
}

// ---------------------------------------------------------------------------
// Kernel 1: value(SRC,BSZ,E) fp32 -> vt[b][e][s] bf16   (64x64 tile / block)
// Lane mapping chosen so LDS writes are exactly 2-way bank aliased (free):
//   write bank = (16*(c4l&1) + 4*j + (sl>>1)) % 32  -> 2 lanes/bank.
// ---------------------------------------------------------------------------
__global__ __launch_bounds__(256) void transpose_v(
    const float* __restrict__ value, unsigned short* __restrict__ vt)
{
    __shared__ unsigned short tile[64 * 72];   // pitch 72 (dword pitch 36)
    const int b  = blockIdx.z;
    const int e0 = blockIdx.y * 64;
    const int s0 = blockIdx.x * 64;
    const int tid = threadIdx.x;

    #pragma unroll
    for (int i = 0; i < 4; ++i) {
        int lin = i * 256 + tid;                       // 0..1023
        int sl  = (lin >> 2) & 63;                     // s-local
        int c4  = ((lin >> 8) << 2) | (lin & 3);       // e float4 index 0..15
        f4 v = *(const f4*)(value + (size_t)(s0 + sl) * (BSZ * E)
                                  + (size_t)b * E + e0 + c4 * 4);
        #pragma unroll
        for (int j = 0; j < 4; ++j)
            tile[(c4 * 4 + j) * 72 + sl] = f2b(v[j]);  // transposed store
    }
    __syncthreads();
    #pragma unroll
    for (int i = 0; i < 2; ++i) {
        int lin = i * 256 + tid;      // 0..511
        int er  = lin >> 3;           // e-local 0..63
        int c8  = lin & 7;            // s vec index
        u16x8 v = *(const u16x8*)(tile + er * 72 + c8 * 8);
        *(u16x8*)(vt + (size_t)b * E * SRC + (size_t)(e0 + er) * SRC + s0 + c8 * 8) = v;
    }
}

// ---------------------------------------------------------------------------
// Kernel 2: attn_weights = proposal_mask copy (fp32) + optional bf16 mask out
// ---------------------------------------------------------------------------
__global__ __launch_bounds__(256) void copy_mask(
    const f4* __restrict__ src, f4* __restrict__ dst,
    u16x4* __restrict__ mbf, int do_bf16, int nvec)
{
    int i      = blockIdx.x * blockDim.x + threadIdx.x;
    int stride = gridDim.x * blockDim.x;
    for (; i < nvec; i += stride) {
        f4 v = src[i];
        dst[i] = v;
        if (do_bf16) {
            u16x4 m;
            m[0] = f2b(v[0]); m[1] = f2b(v[1]); m[2] = f2b(v[2]); m[3] = f2b(v[3]);
            mbf[i] = m;
        }
    }
}

// ---------------------------------------------------------------------------
// Kernel 3 (primary): C_b = M_b(256x4096) @ V_b(4096x256), mask pre-cvt bf16
// 512 blocks x 512 thr; 32x32 tile; 8 waves split K; padded LDS reduction.
// ---------------------------------------------------------------------------
#define SLAB 1152   // 32 rows * 36 dwords (pad: write bank 2-way, free)

__device__ inline void gemm1_epilogue(float* red, f32x4 acc00, f32x4 acc01,
                                      f32x4 acc10, f32x4 acc11,
                                      int w, int quad, int l15, int tid,
                                      int b, int t0, int e0,
                                      unsigned short* __restrict__ c_red)
{
    float* slab = red + w * SLAB;
    #pragma unroll
    for (int r = 0; r < 4; ++r) {
        slab[( 0 + quad * 4 + r) * 36 + ( 0 + l15)] = acc00[r];
        slab[( 0 + quad * 4 + r) * 36 + (16 + l15)] = acc01[r];
        slab[(16 + quad * 4 + r) * 36 + ( 0 + l15)] = acc10[r];
        slab[(16 + quad * 4 + r) * 36 + (16 + l15)] = acc11[r];
    }
    __syncthreads();
    #pragma unroll
    for (int i = 0; i < 2; ++i) {
        int idx = i * 512 + tid;           // 0..1023
        int row = idx >> 5, col = idx & 31;
        float s = 0.f;
        #pragma unroll
        for (int ww = 0; ww < 8; ++ww) s += red[ww * SLAB + row * 36 + col];
        c_red[(size_t)b * TGT * E + (size_t)(t0 + row) * E + (e0 + col)] = f2b(s);
    }
}

__global__ __launch_bounds__(512) void gemm1_bf16(
    const unsigned short* __restrict__ maskb,
    const unsigned short* __restrict__ vt,
    unsigned short* __restrict__ c_red)
{
    __shared__ float red[8 * SLAB];
    const int bx   = blockIdx.x;
    const int b    = bx & 7;
    const int tile = bx >> 3;
    const int t0   = (tile >> 3) * 32;
    const int e0   = (tile & 7) * 32;
    const int tid  = threadIdx.x;
    const int w    = tid >> 6;
    const int lane = tid & 63;
    const int quad = lane >> 4;
    const int l15  = lane & 15;

    const unsigned short* ma0 = maskb + (size_t)b * TGT * SRC + (size_t)(t0 + l15) * SRC;
    const unsigned short* ma1 = ma0 + 16 * SRC;
    const unsigned short* vb0 = vt  + (size_t)b * E * SRC + (size_t)(e0 + l15) * SRC;
    const unsigned short* vb1 = vb0 + 16 * SRC;
    const int kbase = w * 512 + quad * 8;

    f32x4 acc00 = {}, acc01 = {}, acc10 = {}, acc11 = {};
    #pragma unroll
    for (int g = 0; g < 4; ++g) {
        bf16x8 a0[4], a1[4], b0[4], b1[4];
        #pragma unroll
        for (int j = 0; j < 4; ++j) {
            int k = kbase + (g * 4 + j) * 32;
            a0[j] = *(const bf16x8*)(ma0 + k);
            a1[j] = *(const bf16x8*)(ma1 + k);
            b0[j] = *(const bf16x8*)(vb0 + k);
            b1[j] = *(const bf16x8*)(vb1 + k);
        }
        #pragma unroll
        for (int j = 0; j < 4; ++j) {
            acc00 = __builtin_amdgcn_mfma_f32_16x16x32_bf16(a0[j], b0[j], acc00, 0, 0, 0);
            acc01 = __builtin_amdgcn_mfma_f32_16x16x32_bf16(a0[j], b1[j], acc01, 0, 0, 0);
            acc10 = __builtin_amdgcn_mfma_f32_16x16x32_bf16(a1[j], b0[j], acc10, 0, 0, 0);
            acc11 = __builtin_amdgcn_mfma_f32_16x16x32_bf16(a1[j], b1[j], acc11, 0, 0, 0);
        }
    }
    gemm1_epilogue(red, acc00, acc01, acc10, acc11, w, quad, l15, tid, b, t0, e0, c_red);
}

// fallback: mask read as fp32 + inline cvt (used only if ws too small)
__global__ __launch_bounds__(512) void gemm1_f32(
    const float* __restrict__ mask,
    const unsigned short* __restrict__ vt,
    unsigned short* __restrict__ c_red)
{
    __shared__ float red[8 * SLAB];
    const int bx   = blockIdx.x;
    const int b    = bx & 7;
    const int tile = bx >> 3;
    const int t0   = (tile >> 3) * 32;
    const int e0   = (tile & 7) * 32;
    const int tid  = threadIdx.x;
    const int w    = tid >> 6;
    const int lane = tid & 63;
    const int quad = lane >> 4;
    const int l15  = lane & 15;

    const float* ma0 = mask + (size_t)b * TGT * SRC + (size_t)(t0 + l15) * SRC;
    const float* ma1 = ma0 + 16 * SRC;
    const unsigned short* vb0 = vt + (size_t)b * E * SRC + (size_t)(e0 + l15) * SRC;
    const unsigned short* vb1 = vb0 + 16 * SRC;
    const int kbase = w * 512 + quad * 8;

    f32x4 acc00 = {}, acc01 = {}, acc10 = {}, acc11 = {};
    #pragma unroll
    for (int g = 0; g < 4; ++g) {
        bf16x8 a0[4], a1[4], b0[4], b1[4];
        #pragma unroll
        for (int j = 0; j < 4; ++j) {
            int k = kbase + (g * 4 + j) * 32;
            a0[j] = cvt8v(ma0 + k);
            a1[j] = cvt8v(ma1 + k);
            b0[j] = *(const bf16x8*)(vb0 + k);
            b1[j] = *(const bf16x8*)(vb1 + k);
        }
        #pragma unroll
        for (int j = 0; j < 4; ++j) {
            acc00 = __builtin_amdgcn_mfma_f32_16x16x32_bf16(a0[j], b0[j], acc00, 0, 0, 0);
            acc01 = __builtin_amdgcn_mfma_f32_16x16x32_bf16(a0[j], b1[j], acc01, 0, 0, 0);
            acc10 = __builtin_amdgcn_mfma_f32_16x16x32_bf16(a1[j], b0[j], acc10, 0, 0, 0);
            acc11 = __builtin_amdgcn_mfma_f32_16x16x32_bf16(a1[j], b1[j], acc11, 0, 0, 0);
        }
    }
    gemm1_epilogue(red, acc00, acc01, acc10, acc11, w, quad, l15, tid, b, t0, e0, c_red);
}

// ---------------------------------------------------------------------------
// Kernel 4: out[t,b,:] = C_b[t,:] @ W^T + bias   (A = bf16 cred, B = fp32 W)
// ---------------------------------------------------------------------------
__global__ __launch_bounds__(256) void gemm2(
    const unsigned short* __restrict__ c_red,
    const float* __restrict__ wgt,
    const float* __restrict__ bias,
    float* __restrict__ out0)
{
    const int tid  = threadIdx.x;
    const int wv   = tid >> 6;
    const int lane = tid & 63;
    const int tau  = blockIdx.x * 4 + wv;   // 0..2047
    const int b    = tau >> 8;
    const int rem  = tau & 255;
    const int t0   = (rem >> 4) * 16;
    const int e0   = (rem & 15) * 16;
    const int quad = lane >> 4;
    const int l15  = lane & 15;

    const unsigned short* arow = c_red + (size_t)b * TGT * E + (size_t)(t0 + l15) * E + quad * 8;
    const float*          brow = wgt + (size_t)(e0 + l15) * E + quad * 8;

    f32x4 acc = {};
    #pragma unroll
    for (int ks = 0; ks < 8; ++ks) {
        bf16x8 a  = *(const bf16x8*)(arow + ks * 32);
        bf16x8 bb = cvt8v(brow + ks * 32);
        acc = __builtin_amdgcn_mfma_f32_16x16x32_bf16(a, bb, acc, 0, 0, 0);
    }

    const float bval = bias[e0 + l15];
    #pragma unroll
    for (int r = 0; r < 4; ++r) {
        int t = t0 + quad * 4 + r;
        int e = e0 + l15;
        out0[(size_t)t * (BSZ * E) + (size_t)b * E + e] = acc[r] + bval;
    }
}

// ---------------------------------------------------------------------------
extern "C" void kernel_launch(void* const* d_in, const int* in_sizes, int n_in,
                              void* d_out, int out_size, void* d_ws, size_t ws_size,
                              hipStream_t stream)
{
    // inputs: 0=query(unused) 1=key(unused) 2=value 3=proposal_mask 4=W 5=bias
    const float* value = (const float*)d_in[2];
    const float* mask  = (const float*)d_in[3];
    const float* wgt   = (const float*)d_in[4];
    const float* bias  = (const float*)d_in[5];

    float* out0 = (float*)d_out;                              // (256,8,256)
    float* out1 = (float*)d_out + (size_t)TGT * BSZ * E;      // (8,256,4096)

    // ws layout: vt (16 MiB) | cred bf16 (1 MiB) | maskb (16 MiB, optional)
    unsigned short* vt    = (unsigned short*)d_ws;
    unsigned short* cred  = vt + (size_t)BSZ * E * SRC;
    unsigned short* maskb = cred + (size_t)BSZ * TGT * E;
    const size_t need_bf16 = ((size_t)BSZ * E * SRC + (size_t)BSZ * TGT * E
                              + (size_t)BSZ * TGT * SRC) * 2;
    const int have_bf16 = ws_size >= need_bf16;

    transpose_v<<<dim3(SRC / 64, E / 64, BSZ), 256, 0, stream>>>(value, vt);
    copy_mask<<<2048, 256, 0, stream>>>((const f4*)mask, (f4*)out1,
                                        (u16x4*)maskb, have_bf16,
                                        BSZ * TGT * SRC / 4);
    if (have_bf16)
        gemm1_bf16<<<512, 512, 0, stream>>>(maskb, vt, cred);
    else
        gemm1_f32<<<512, 512, 0, stream>>>(mask, vt, cred);
    gemm2<<<512, 256, 0, stream>>>(cred, wgt, bias, out0);
}

// Round 4
// 170.041 us; speedup vs baseline: 1.1171x; 1.0423x over previous
//
#include <hip/hip_runtime.h>
#include <hip/hip_bf16.h>

#define TGT 256
#define BSZ 8
#define E   256
#define SRC 4096

typedef __attribute__((ext_vector_type(8))) short           bf16x8;
typedef __attribute__((ext_vector_type(4))) float           f32x4;
typedef __attribute__((ext_vector_type(4))) float           f4;
typedef __attribute__((ext_vector_type(8))) unsigned short  u16x8;
typedef __attribute__((ext_vector_type(4))) unsigned short  u16x4;

__device__ inline unsigned short f2b(float x) {
    union { __hip_bfloat16 h; unsigned short u; } cv;
    cv.h = __float2bfloat16(x);
    return cv.u;
}

// load 8 contiguous floats, convert to bf16x8 fragment
__device__ inline bf16x8 cvt8v(const float* __restrict__ p) {
    f4 lo = *(const f4*)p;
    f4 hi = *(const f4*)(p + 4);
    bf16x8 r;
    #pragma unroll
    for (int j = 0; j < 4; ++j) {
        r[j]     = (short)f2b(lo[j]);
        r[4 + j] = (short)f2b(hi[j]);
    }
    return r;
}

// ---------------------------------------------------------------------------
// Kernel 1: value(SRC,BSZ,E) fp32 -> vt[b][e][s] bf16   (64x64 tile / block)
// LDS writes exactly 2-way bank aliased (free, m136). [verified round 3]
// ---------------------------------------------------------------------------
__global__ __launch_bounds__(256) void transpose_v(
    const float* __restrict__ value, unsigned short* __restrict__ vt)
{
    __shared__ unsigned short tile[64 * 72];   // pitch 72 (dword pitch 36)
    const int b  = blockIdx.z;
    const int e0 = blockIdx.y * 64;
    const int s0 = blockIdx.x * 64;
    const int tid = threadIdx.x;

    #pragma unroll
    for (int i = 0; i < 4; ++i) {
        int lin = i * 256 + tid;                       // 0..1023
        int sl  = (lin >> 2) & 63;                     // s-local
        int c4  = ((lin >> 8) << 2) | (lin & 3);       // e float4 index 0..15
        f4 v = *(const f4*)(value + (size_t)(s0 + sl) * (BSZ * E)
                                  + (size_t)b * E + e0 + c4 * 4);
        #pragma unroll
        for (int j = 0; j < 4; ++j)
            tile[(c4 * 4 + j) * 72 + sl] = f2b(v[j]);  // transposed store
    }
    __syncthreads();
    #pragma unroll
    for (int i = 0; i < 2; ++i) {
        int lin = i * 256 + tid;      // 0..511
        int er  = lin >> 3;           // e-local 0..63
        int c8  = lin & 7;            // s vec index
        u16x8 v = *(const u16x8*)(tile + er * 72 + c8 * 8);
        *(u16x8*)(vt + (size_t)b * E * SRC + (size_t)(e0 + er) * SRC + s0 + c8 * 8) = v;
    }
}

// ---------------------------------------------------------------------------
// Kernel 2: fused  (a) out1 = mask  (b) partial[kc] = M_b[t-tile, kc] @ V_b[kc]
// Block = (b, 32-row t-tile, 1024-wide K chunk).  256 blocks, 512 thr.
// A (mask) staged fp32->bf16 into double-buffered LDS; mask read ONCE,
// out1 written in the same pass. 8 waves each own 32 E-columns -> no
// cross-wave reduction. B frags straight from vt (bf16, k-contiguous),
// prefetched one k-sub ahead.
// ---------------------------------------------------------------------------
#define AP 136   // LDS pitch in u16: 272 B = 17*16 (b128-aligned), 2-way banks

__global__ __launch_bounds__(512) void gemm1_fused(
    const float* __restrict__ mask,
    const unsigned short* __restrict__ vt,
    float* __restrict__ out1,
    float* __restrict__ part)
{
    __shared__ unsigned short As[2][32 * AP];   // 2 x 8.5 KB
    const int bx  = blockIdx.x;
    const int b   = bx & 7;              // XCD swizzle
    const int tt  = (bx >> 3) & 7;
    const int kc  = bx >> 6;             // 0..3
    const int t0  = tt * 32;
    const int k0  = kc * 1024;
    const int tid = threadIdx.x;
    const int w    = tid >> 6;
    const int lane = tid & 63;
    const int quad = lane >> 4;
    const int l15  = lane & 15;

    const float* mbase = mask + (size_t)b * TGT * SRC + (size_t)t0 * SRC + k0;
    float*       obase = out1 + (size_t)b * TGT * SRC + (size_t)t0 * SRC + k0;
    // staging split: thread -> 2 f4 per 32x128 sub-chunk
    const int sr0 = tid >> 5, sc0 = (tid & 31) * 4;          // i=0: row tid>>5
    const int sr1 = (512 + tid) >> 5, sc1 = sc0;             // i=1

    // wave-private B rows (e = w*32 + {0,16} + l15), k-contiguous bf16
    const unsigned short* vrow0 = vt + (size_t)b * E * SRC
                                + (size_t)(w * 32 + l15) * SRC + k0;
    const unsigned short* vrow1 = vrow0 + 16 * SRC;

    f32x4 acc00 = {}, acc01 = {}, acc10 = {}, acc11 = {};

    // ---- prologue: stage k-sub 0, prefetch B for k-sub 0
    {
        f4 v0 = *(const f4*)(mbase + (size_t)sr0 * SRC + sc0);
        f4 v1 = *(const f4*)(mbase + (size_t)(sr1 & 31) * SRC + sc1);
        *(f4*)(obase + (size_t)sr0 * SRC + sc0) = v0;
        *(f4*)(obase + (size_t)(sr1 & 31) * SRC + sc1) = v1;
        unsigned short* d0 = &As[0][sr0 * AP + sc0];
        unsigned short* d1 = &As[0][(sr1 & 31) * AP + sc1];
        #pragma unroll
        for (int j = 0; j < 4; ++j) { d0[j] = f2b(v0[j]); d1[j] = f2b(v1[j]); }
    }
    bf16x8 B0[4], B1[4];
    #pragma unroll
    for (int j = 0; j < 4; ++j) {
        B0[j] = *(const bf16x8*)(vrow0 + j * 32 + quad * 8);
        B1[j] = *(const bf16x8*)(vrow1 + j * 32 + quad * 8);
    }
    __syncthreads();

    for (int ks = 0; ks < 8; ++ks) {
        const int slab = ks & 1;
        // prefetch B frags for ks+1 (global, latency overlapped with MFMA)
        bf16x8 nB0[4], nB1[4];
        if (ks < 7) {
            #pragma unroll
            for (int j = 0; j < 4; ++j) {
                nB0[j] = *(const bf16x8*)(vrow0 + (ks + 1) * 128 + j * 32 + quad * 8);
                nB1[j] = *(const bf16x8*)(vrow1 + (ks + 1) * 128 + j * 32 + quad * 8);
            }
        }
        // stage loads for ks+1 (mask fp32 + verbatim out1 store)
        f4 v0, v1;
        if (ks < 7) {
            v0 = *(const f4*)(mbase + (size_t)sr0 * SRC + (ks + 1) * 128 + sc0);
            v1 = *(const f4*)(mbase + (size_t)(sr1 & 31) * SRC + (ks + 1) * 128 + sc1);
        }

        // compute k-sub ks from LDS slab
        #pragma unroll
        for (int j = 0; j < 4; ++j) {
            bf16x8 a0 = *(const bf16x8*)(&As[slab][(     l15) * AP + j * 32 + quad * 8]);
            bf16x8 a1 = *(const bf16x8*)(&As[slab][(16 + l15) * AP + j * 32 + quad * 8]);
            acc00 = __builtin_amdgcn_mfma_f32_16x16x32_bf16(a0, B0[j], acc00, 0, 0, 0);
            acc01 = __builtin_amdgcn_mfma_f32_16x16x32_bf16(a0, B1[j], acc01, 0, 0, 0);
            acc10 = __builtin_amdgcn_mfma_f32_16x16x32_bf16(a1, B0[j], acc10, 0, 0, 0);
            acc11 = __builtin_amdgcn_mfma_f32_16x16x32_bf16(a1, B1[j], acc11, 0, 0, 0);
        }

        if (ks < 7) {
            *(f4*)(obase + (size_t)sr0 * SRC + (ks + 1) * 128 + sc0) = v0;
            *(f4*)(obase + (size_t)(sr1 & 31) * SRC + (ks + 1) * 128 + sc1) = v1;
            unsigned short* d0 = &As[slab ^ 1][sr0 * AP + sc0];
            unsigned short* d1 = &As[slab ^ 1][(sr1 & 31) * AP + sc1];
            #pragma unroll
            for (int j = 0; j < 4; ++j) { d0[j] = f2b(v0[j]); d1[j] = f2b(v1[j]); }
            #pragma unroll
            for (int j = 0; j < 4; ++j) { B0[j] = nB0[j]; B1[j] = nB1[j]; }
        }
        __syncthreads();
    }

    // epilogue: wave-private 32x64... (32 rows x 32 cols) fp32 partial
    // D layout: col = lane&15, row = quad*4 + reg  [verified m89/m91]
    float* pb = part + ((size_t)kc * BSZ + b) * TGT * E;
    #pragma unroll
    for (int r = 0; r < 4; ++r) {
        int rr0 = t0 + quad * 4 + r;
        int rr1 = rr0 + 16;
        int c0  = w * 32 + l15;
        pb[(size_t)rr0 * E + c0]      = acc00[r];
        pb[(size_t)rr0 * E + c0 + 16] = acc01[r];
        pb[(size_t)rr1 * E + c0]      = acc10[r];
        pb[(size_t)rr1 * E + c0 + 16] = acc11[r];
    }
}

// ---------------------------------------------------------------------------
// Kernel 3: out0[t,b,:] = (sum_kc part[kc])[b,t,:] @ W^T + bias
// wave per 16x16 tile; A = fp32 4-partial sum -> bf16; B = fp32 W -> bf16.
// ---------------------------------------------------------------------------
#define PSTRIDE ((size_t)BSZ * TGT * E)

__global__ __launch_bounds__(256) void gemm2(
    const float* __restrict__ part,
    const float* __restrict__ wgt,
    const float* __restrict__ bias,
    float* __restrict__ out0)
{
    const int tid  = threadIdx.x;
    const int wv   = tid >> 6;
    const int lane = tid & 63;
    const int tau  = blockIdx.x * 4 + wv;   // 0..2047
    const int b    = tau >> 8;
    const int rem  = tau & 255;
    const int t0   = (rem >> 4) * 16;
    const int e0   = (rem & 15) * 16;
    const int quad = lane >> 4;
    const int l15  = lane & 15;

    const float* arow = part + (size_t)b * TGT * E + (size_t)(t0 + l15) * E + quad * 8;
    const float* brow = wgt + (size_t)(e0 + l15) * E + quad * 8;

    f32x4 acc = {};
    #pragma unroll
    for (int ks = 0; ks < 8; ++ks) {
        const float* ap = arow + ks * 32;
        f4 lo = *(const f4*)(ap);
        f4 hi = *(const f4*)(ap + 4);
        #pragma unroll
        for (int p = 1; p < 4; ++p) {
            lo += *(const f4*)(ap + p * PSTRIDE);
            hi += *(const f4*)(ap + p * PSTRIDE + 4);
        }
        bf16x8 a;
        #pragma unroll
        for (int j = 0; j < 4; ++j) {
            a[j]     = (short)f2b(lo[j]);
            a[4 + j] = (short)f2b(hi[j]);
        }
        bf16x8 bb = cvt8v(brow + ks * 32);
        acc = __builtin_amdgcn_mfma_f32_16x16x32_bf16(a, bb, acc, 0, 0, 0);
    }

    const float bval = bias[e0 + l15];
    #pragma unroll
    for (int r = 0; r < 4; ++r) {
        int t = t0 + quad * 4 + r;
        int e = e0 + l15;
        out0[(size_t)t * (BSZ * E) + (size_t)b * E + e] = acc[r] + bval;
    }
}

// ---------------------------------------------------------------------------
extern "C" void kernel_launch(void* const* d_in, const int* in_sizes, int n_in,
                              void* d_out, int out_size, void* d_ws, size_t ws_size,
                              hipStream_t stream)
{
    // inputs: 0=query(unused) 1=key(unused) 2=value 3=proposal_mask 4=W 5=bias
    const float* value = (const float*)d_in[2];
    const float* mask  = (const float*)d_in[3];
    const float* wgt   = (const float*)d_in[4];
    const float* bias  = (const float*)d_in[5];

    float* out0 = (float*)d_out;                              // (256,8,256)
    float* out1 = (float*)d_out + (size_t)TGT * BSZ * E;      // (8,256,4096)

    // ws layout: vt bf16 (16.8 MB) | part fp32 [4][b][t][e] (8 MB)
    unsigned short* vt   = (unsigned short*)d_ws;
    float*          part = (float*)(vt + (size_t)BSZ * E * SRC);

    transpose_v<<<dim3(SRC / 64, E / 64, BSZ), 256, 0, stream>>>(value, vt);
    gemm1_fused<<<256, 512, 0, stream>>>(mask, vt, out1, part);
    gemm2<<<512, 256, 0, stream>>>(part, wgt, bias, out0);
}